// Round 3
// baseline (142.397 us; speedup 1.0000x reference)
//
#include <hip/hip_runtime.h>
#include <hip/hip_bf16.h>

typedef __bf16 bf16x8 __attribute__((ext_vector_type(8)));
typedef __bf16 bf16x4 __attribute__((ext_vector_type(4)));
typedef float  float4v __attribute__((ext_vector_type(4)));

#define MFMA16 __builtin_amdgcn_mfma_f32_16x16x32_bf16

__device__ __forceinline__ float bf2f(unsigned short u){
  union { unsigned int i; float f; } x; x.i = ((unsigned int)u) << 16; return x.f;
}
__device__ __forceinline__ unsigned short f2bf(float f){
  union { float f; unsigned int i; } x; x.f = f;
  unsigned int r = x.i + 0x7FFFu + ((x.i >> 16) & 1u);
  return (unsigned short)(r >> 16);
}
__device__ __forceinline__ float ldin(const void* p, int i, bool isbf){
  return isbf ? bf2f(((const unsigned short*)p)[i]) : ((const float*)p)[i];
}
__device__ __forceinline__ float frcp(float x){ return __builtin_amdgcn_rcpf(x); }

// ws layout (bytes):
//   0       : meta int[2] {isbf, max_step}
//   1024    : KmHi bf16[64*64]   relu(K)[l][a] at [l][a]
//   9216    : KTHi bf16[64*64]   relu(K)[l][a] at [a][l]
//   17408   : gAF  bf16[4096*64]
//   541696  : gLF  bf16[4096*64]
//   1065984 : W2T  bf16[128][4160]  (k<4096 -> Km*u ; 4096..4159 -> e)
#define W2T_STRIDE 4160

// ---------------- prep ----------------
__global__ __launch_bounds__(256) void k_prep(
    const void* K, const void* AT, const void* u, const void* e,
    const int* msin, __bf16* KmHi, __bf16* KTHi, __bf16* W2T, int* meta)
{
  int tid = threadIdx.x, bid = blockIdx.x;
  int ok = 0;
  if (tid < 64){
    float v = bf2f(((const unsigned short*)AT)[tid]);
    ok = (v >= 0.f && v <= 1.0f) ? 1 : 0;
  }
  int cnt = __syncthreads_count(ok);
  bool isbf = (cnt >= 60);

  if (bid < 256){
    // W2T u-region: transpose tile k:64 x y:32, fold Km
    int k0 = (bid >> 2) * 64, y0 = (bid & 3) * 32;
    __shared__ float sT[64 * 33];
    #pragma unroll
    for (int i = 0; i < 8; ++i){
      int flat = i * 256 + tid;
      int r = flat >> 5, c = flat & 31;
      sT[r * 33 + c] = ldin(u, (k0 + r) * 128 + (y0 + c), isbf);
    }
    __syncthreads();
    int l = k0 >> 6;
    #pragma unroll
    for (int i = 0; i < 8; ++i){
      int flat = i * 256 + tid;
      int yl = flat >> 6, kl = flat & 63;
      float km = ldin(K, l * 64 + kl, isbf); km = km > 0.f ? km : 0.f;
      W2T[(y0 + yl) * W2T_STRIDE + (k0 + kl)] = (__bf16)(km * sT[kl * 33 + yl]);
    }
  } else if (bid == 256){
    // Km + KT via LDS transpose (all coalesced)
    __shared__ float sK[64 * 65];
    #pragma unroll
    for (int i = 0; i < 16; ++i){
      int idx = i * 256 + tid;
      int l = idx >> 6, a = idx & 63;
      float v = ldin(K, idx, isbf); v = v > 0.f ? v : 0.f;
      sK[l * 65 + a] = v;
      KmHi[idx] = (__bf16)v;
    }
    __syncthreads();
    #pragma unroll
    for (int i = 0; i < 16; ++i){
      int idx = i * 256 + tid;
      int a = idx >> 6, l2 = idx & 63;
      KTHi[idx] = (__bf16)sK[l2 * 65 + a];
    }
    if (tid == 0){
      meta[0] = isbf ? 1 : 0;
      int mi = msin[0];
      if (mi <= 0 || mi > 1000000){
        float mf = ((const float*)msin)[0];
        mi = (mf > 0.f && mf < 1.0e6f) ? (int)mf : 50;
      }
      meta[1] = mi;
    }
  } else {
    // e-region via LDS transpose
    __shared__ float sE[64 * 133];
    #pragma unroll
    for (int i = 0; i < 32; ++i){
      int idx = i * 256 + tid;
      int a = idx >> 7, y = idx & 127;
      sE[a * 133 + y] = ldin(e, idx, isbf);
    }
    __syncthreads();
    #pragma unroll
    for (int i = 0; i < 32; ++i){
      int idx = i * 256 + tid;
      int y = idx >> 6, a = idx & 63;
      W2T[y * W2T_STRIDE + 4096 + a] = (__bf16)sE[a * 133 + y];
    }
  }
}

// ---------------- iteration ----------------
// One wave fully owns one chain (AF or LF) for 16 batch rows. No barriers.
// State X[dim][row] lives in wave-private LDS as [row][dim], row stride 72.
// half-step: out = V * rcp(M @ X + 1), M preloaded as 4x2 A-fragments.
template<bool SPLIT>
__device__ __forceinline__ void halfstep(
    const bf16x8 (&A)[4][2], const float4v (&V)[4],
    __bf16* sH, __bf16* sL, int rb, int wb)
{
  bf16x8 bh0 = *(const bf16x8*)(sH + rb);
  bf16x8 bh1 = *(const bf16x8*)(sH + rb + 32);
  const float4v ones = {1.f, 1.f, 1.f, 1.f};
  float4v c[4];
  #pragma unroll
  for (int T = 0; T < 4; ++T) c[T] = MFMA16(A[T][0], bh0, ones, 0, 0, 0);
  #pragma unroll
  for (int T = 0; T < 4; ++T) c[T] = MFMA16(A[T][1], bh1, c[T], 0, 0, 0);
  if (SPLIT){
    bf16x8 bl0 = *(const bf16x8*)(sL + rb);
    bf16x8 bl1 = *(const bf16x8*)(sL + rb + 32);
    const float4v zero = {0.f, 0.f, 0.f, 0.f};
    float4v d[4];
    #pragma unroll
    for (int T = 0; T < 4; ++T) d[T] = MFMA16(A[T][0], bl0, zero, 0, 0, 0);
    #pragma unroll
    for (int T = 0; T < 4; ++T) d[T] = MFMA16(A[T][1], bl1, d[T], 0, 0, 0);
    #pragma unroll
    for (int T = 0; T < 4; ++T) c[T] += d[T];
  }
  #pragma unroll
  for (int T = 0; T < 4; ++T){
    bf16x4 h, lo;
    #pragma unroll
    for (int r = 0; r < 4; ++r){
      float o = V[T][r] * frcp(c[T][r]);
      __bf16 hh = (__bf16)o;
      h[r] = hh;
      if (SPLIT) lo[r] = (__bf16)(o - (float)hh);
    }
    *(bf16x4*)(sH + wb + 16 * T) = h;
    if (SPLIT) *(bf16x4*)(sL + wb + 16 * T) = lo;
  }
}

__global__ __launch_bounds__(128, 1) void k_iter(
    const void* LT, const void* AT, const __bf16* KmHi, const __bf16* KTHi,
    const int* meta, __bf16* gAF, __bf16* gLF)
{
  __shared__ __attribute__((aligned(16))) __bf16 sHi[2][16 * 72];
  __shared__ __attribute__((aligned(16))) __bf16 sLo[2][16 * 72];
  const int tid = threadIdx.x, w = tid >> 6, lane = tid & 63;
  const int lr = lane & 15, q = lane >> 4;
  const int row0 = blockIdx.x * 16;
  __bf16* sH = sHi[w];
  __bf16* sL = sLo[w];

  const bf16x4 z4 = {(__bf16)0.f, (__bf16)0.f, (__bf16)0.f, (__bf16)0.f};
  for (int i = lane; i < 288; i += 64){
    *(bf16x4*)(sH + 4 * i) = z4;
    *(bf16x4*)(sL + 4 * i) = z4;
  }

  const int isbf = meta[0];
  const int ms   = meta[1];

  // chain 0 (AF): gemm1 = Km, V1 = LT[row]; gemm2 = KT, V2 = ATm
  // chain 1 (LF): gemm1 = KT, V1 = ATm;     gemm2 = Km, V2 = LT[row]
  const __bf16* M1 = w ? KTHi : KmHi;
  const __bf16* M2 = w ? KmHi : KTHi;
  bf16x8 a1[4][2], a2[4][2];
  #pragma unroll
  for (int T = 0; T < 4; ++T)
    #pragma unroll
    for (int ks = 0; ks < 2; ++ks){
      int o = (16 * T + lr) * 64 + ks * 32 + q * 8;
      a1[T][ks] = *(const bf16x8*)(M1 + o);
      a2[T][ks] = *(const bf16x8*)(M2 + o);
    }

  float4v ltv[4], atv[4];
  if (isbf){
    const unsigned short* lt = (const unsigned short*)LT + (row0 + lr) * 64;
    const unsigned short* at = (const unsigned short*)AT;
    #pragma unroll
    for (int T = 0; T < 4; ++T)
      #pragma unroll
      for (int r = 0; r < 4; ++r){
        int d = 16 * T + q * 4 + r;
        ltv[T][r] = bf2f(lt[d]);
        atv[T][r] = fmaxf(bf2f(at[d]), 0.f);
      }
  } else {
    const float* lt = (const float*)LT + (row0 + lr) * 64;
    const float* at = (const float*)AT;
    #pragma unroll
    for (int T = 0; T < 4; ++T){
      ltv[T] = *(const float4v*)(lt + 16 * T + q * 4);
      float4v a = *(const float4v*)(at + 16 * T + q * 4);
      #pragma unroll
      for (int r = 0; r < 4; ++r) atv[T][r] = fmaxf(a[r], 0.f);
    }
  }
  float4v V1[4], V2[4];
  #pragma unroll
  for (int T = 0; T < 4; ++T){
    V1[T] = w ? atv[T] : ltv[T];
    V2[T] = w ? ltv[T] : atv[T];
  }

  const int rb = lr * 72 + q * 8;
  const int wb = lr * 72 + q * 4;

  const int nPlain = ms > 6 ? ms - 6 : 0;
  const int nSplit = ms - nPlain + 1;   // + final extra double-step
  for (int s = 0; s < nPlain; ++s){
    halfstep<false>(a1, V1, sH, sL, rb, wb);
    halfstep<false>(a2, V2, sH, sL, rb, wb);
  }
  for (int s = 0; s < nSplit; ++s){
    halfstep<true>(a1, V1, sH, sL, rb, wb);
    halfstep<true>(a2, V2, sH, sL, rb, wb);
  }

  // coalesced write-out of final state (hi)
  __bf16* gX = (w ? gLF : gAF) + row0 * 64;
  const int lrow = lane >> 2, seg = lane & 3;
  bf16x8 v0 = *(const bf16x8*)(sH + lrow * 72 + seg * 16);
  bf16x8 v1 = *(const bf16x8*)(sH + lrow * 72 + seg * 16 + 8);
  *(bf16x8*)(gX + lrow * 64 + seg * 16) = v0;
  *(bf16x8*)(gX + lrow * 64 + seg * 16 + 8) = v1;
}

// ---------------- epilogue ----------------
// block = 32 rows x 64 y-cols; wave = 16 rows x 32 y-cols.
// y[row][y] = sum_k D[row][k] * W2T[y][k] + b[y],
// D[row][l*64+a] = LF[row][l]*AF[row][a]; k in [4096,4160) uses AF directly (e-term).
__global__ __launch_bounds__(256) void k_epi(
    const __bf16* gAF, const __bf16* gLF, const __bf16* W2T,
    const void* bvec, const int* meta, void* out)
{
  __shared__ __attribute__((aligned(16))) __bf16 sAF[32 * 72], sLF[32 * 72];
  const int tid = threadIdx.x, wave = tid >> 6, lane = tid & 63;
  const int lr = lane & 15, q = lane >> 4;
  const int rg = blockIdx.x >> 1, yh = blockIdx.x & 1;
  const int row0 = rg * 32;
  const int isbf = meta[0];
  {
    int lrow = tid >> 3, seg = tid & 7;
    *(bf16x8*)(sAF + lrow * 72 + seg * 8) =
        *(const bf16x8*)(gAF + (row0 + lrow) * 64 + seg * 8);
    *(bf16x8*)(sLF + lrow * 72 + seg * 8) =
        *(const bf16x8*)(gLF + (row0 + lrow) * 64 + seg * 8);
  }
  __syncthreads();

  const int r0 = (wave & 1) * 16;
  const int y0 = yh * 64 + (wave >> 1) * 32;
  const int rloc = r0 + lr;

  const float bv0 = ldin(bvec, y0 + lr, isbf);
  const float bv1 = ldin(bvec, y0 + 16 + lr, isbf);
  float4v acc0 = {bv0, bv0, bv0, bv0};
  float4v acc1 = {bv1, bv1, bv1, bv1};

  // hoist AF fragments (independent of l)
  bf16x8 af0 = *(const bf16x8*)(sAF + rloc * 72 + q * 8);
  bf16x8 af1 = *(const bf16x8*)(sAF + rloc * 72 + 32 + q * 8);
  float af0f[8], af1f[8];
  #pragma unroll
  for (int j = 0; j < 8; ++j){ af0f[j] = (float)af0[j]; af1f[j] = (float)af1[j]; }

  const __bf16* w0 = W2T + (y0 + lr) * W2T_STRIDE + q * 8;
  const __bf16* w1 = w0 + 16 * W2T_STRIDE;

  #pragma unroll 4
  for (int l = 0; l < 64; ++l){
    const float lf = (float)sLF[rloc * 72 + l];
    bf16x8 aD0, aD1;
    #pragma unroll
    for (int j = 0; j < 8; ++j){
      aD0[j] = (__bf16)(lf * af0f[j]);
      aD1[j] = (__bf16)(lf * af1f[j]);
    }
    const int kb = l * 64;
    bf16x8 b00 = *(const bf16x8*)(w0 + kb);
    bf16x8 b10 = *(const bf16x8*)(w1 + kb);
    bf16x8 b01 = *(const bf16x8*)(w0 + kb + 32);
    bf16x8 b11 = *(const bf16x8*)(w1 + kb + 32);
    acc0 = MFMA16(aD0, b00, acc0, 0, 0, 0);
    acc1 = MFMA16(aD0, b10, acc1, 0, 0, 0);
    acc0 = MFMA16(aD1, b01, acc0, 0, 0, 0);
    acc1 = MFMA16(aD1, b11, acc1, 0, 0, 0);
  }
  // e-term: k = 4096..4159, A-operand = AF raw
  {
    bf16x8 b00 = *(const bf16x8*)(w0 + 4096);
    bf16x8 b10 = *(const bf16x8*)(w1 + 4096);
    bf16x8 b01 = *(const bf16x8*)(w0 + 4096 + 32);
    bf16x8 b11 = *(const bf16x8*)(w1 + 4096 + 32);
    acc0 = MFMA16(af0, b00, acc0, 0, 0, 0);
    acc1 = MFMA16(af0, b10, acc1, 0, 0, 0);
    acc0 = MFMA16(af1, b01, acc0, 0, 0, 0);
    acc1 = MFMA16(af1, b11, acc1, 0, 0, 0);
  }

  const int orow = row0 + r0 + q * 4;
  if (isbf){
    unsigned short* o = (unsigned short*)out;
    #pragma unroll
    for (int r = 0; r < 4; ++r){
      o[(orow + r) * 128 + y0 + lr]      = f2bf(acc0[r]);
      o[(orow + r) * 128 + y0 + 16 + lr] = f2bf(acc1[r]);
    }
  } else {
    float* o = (float*)out;
    #pragma unroll
    for (int r = 0; r < 4; ++r){
      o[(orow + r) * 128 + y0 + lr]      = acc0[r];
      o[(orow + r) * 128 + y0 + 16 + lr] = acc1[r];
    }
  }
}

extern "C" void kernel_launch(void* const* d_in, const int* in_sizes, int n_in,
                              void* d_out, int out_size, void* d_ws, size_t ws_size,
                              hipStream_t stream){
  char* ws = (char*)d_ws;
  int*    meta = (int*)ws;
  __bf16* KmHi = (__bf16*)(ws + 1024);
  __bf16* KTHi = (__bf16*)(ws + 9216);
  __bf16* gAF  = (__bf16*)(ws + 17408);
  __bf16* gLF  = (__bf16*)(ws + 541696);
  __bf16* W2T  = (__bf16*)(ws + 1065984);

  k_prep<<<dim3(258), dim3(256), 0, stream>>>(
      d_in[1], d_in[2], d_in[3], d_in[4], (const int*)d_in[6],
      KmHi, KTHi, W2T, meta);
  k_iter<<<dim3(256), dim3(128), 0, stream>>>(
      d_in[0], d_in[2], KmHi, KTHi, meta, gAF, gLF);
  k_epi<<<dim3(256), dim3(256), 0, stream>>>(
      gAF, gLF, W2T, d_in[5], meta, d_out);
}

// Round 4
// 140.036 us; speedup vs baseline: 1.0169x; 1.0169x over previous
//
#include <hip/hip_runtime.h>
#include <hip/hip_bf16.h>

typedef __bf16 bf16x8 __attribute__((ext_vector_type(8)));
typedef __bf16 bf16x4 __attribute__((ext_vector_type(4)));
typedef float  float4v __attribute__((ext_vector_type(4)));

#define MFMA16 __builtin_amdgcn_mfma_f32_16x16x32_bf16
#define W2T_STRIDE 4160

__device__ __forceinline__ float bf2f(unsigned short u){
  union { unsigned int i; float f; } x; x.i = ((unsigned int)u) << 16; return x.f;
}
__device__ __forceinline__ unsigned short f2bf(float f){
  union { float f; unsigned int i; } x; x.f = f;
  unsigned int r = x.i + 0x7FFFu + ((x.i >> 16) & 1u);
  return (unsigned short)(r >> 16);
}
__device__ __forceinline__ float ldin(const void* p, int i, bool isbf){
  return isbf ? bf2f(((const unsigned short*)p)[i]) : ((const float*)p)[i];
}
__device__ __forceinline__ float frcp(float x){ return __builtin_amdgcn_rcpf(x); }

// ws layout (bytes):
//   0       : gAF bf16[4096*64]
//   524288  : gLF bf16[4096*64]
//   1048576 : W2T bf16[128][4160]  (k<4096 -> Km*u ; 4096..4159 -> e)

// split-bf16 GEMM quarter (R3-proven): 3 indep acc chains, +1 folded into C-init
template<bool SPLIT>
__device__ __forceinline__ void halfstep(
    const bf16x8 (&A)[4][2], const float4v (&V)[4],
    __bf16* sH, __bf16* sL, int rb, int wb)
{
  bf16x8 bh0 = *(const bf16x8*)(sH + rb);
  bf16x8 bh1 = *(const bf16x8*)(sH + rb + 32);
  const float4v ones = {1.f, 1.f, 1.f, 1.f};
  float4v c[4];
  #pragma unroll
  for (int T = 0; T < 4; ++T) c[T] = MFMA16(A[T][0], bh0, ones, 0, 0, 0);
  #pragma unroll
  for (int T = 0; T < 4; ++T) c[T] = MFMA16(A[T][1], bh1, c[T], 0, 0, 0);
  if (SPLIT){
    bf16x8 bl0 = *(const bf16x8*)(sL + rb);
    bf16x8 bl1 = *(const bf16x8*)(sL + rb + 32);
    const float4v zero = {0.f, 0.f, 0.f, 0.f};
    float4v d[4];
    #pragma unroll
    for (int T = 0; T < 4; ++T) d[T] = MFMA16(A[T][0], bl0, zero, 0, 0, 0);
    #pragma unroll
    for (int T = 0; T < 4; ++T) d[T] = MFMA16(A[T][1], bl1, d[T], 0, 0, 0);
    #pragma unroll
    for (int T = 0; T < 4; ++T) c[T] += d[T];
  }
  #pragma unroll
  for (int T = 0; T < 4; ++T){
    bf16x4 h, lo;
    #pragma unroll
    for (int r = 0; r < 4; ++r){
      float o = V[T][r] * frcp(c[T][r]);
      __bf16 hh = (__bf16)o;
      h[r] = hh;
      if (SPLIT) lo[r] = (__bf16)(o - (float)hh);
    }
    *(bf16x4*)(sH + wb + 16 * T) = h;
    if (SPLIT) *(bf16x4*)(sL + wb + 16 * T) = lo;
  }
}

// ---------------- fused prep + iteration ----------------
// grid 386 x 128 threads:
//   bid <  256 : iteration block (2 waves: AF-chain + LF-chain for 16 rows)
//   256..383   : W2T u-region builder (2 tiles of 64k x 32y each)
//   384..385   : W2T e-region builder (64 y-cols each)
__global__ __launch_bounds__(128) void k_fused(
    const void* LT, const void* K, const void* AT, const void* u,
    const void* e, const int* msin,
    __bf16* gAF, __bf16* gLF, __bf16* W2T)
{
  __shared__ __attribute__((aligned(16))) char smem[25856];
  const int tid = threadIdx.x, bid = blockIdx.x;

  int ok = 0;
  if (tid < 64){
    float v = bf2f(((const unsigned short*)AT)[tid]);
    ok = (v >= 0.f && v <= 1.0f) ? 1 : 0;
  }
  int cnt = __syncthreads_count(ok);
  const bool isbf = (cnt >= 60);

  if (bid >= 256){
    if (bid < 384){
      float* sT = (float*)smem;            // 64 x 33
      const int ub = bid - 256;
      const int kl = tid & 63;
      for (int t2 = 0; t2 < 2; ++t2){
        const int t = ub * 2 + t2;
        const int k0 = (t >> 2) * 64, y0 = (t & 3) * 32, l = t >> 2;
        __syncthreads();
        #pragma unroll
        for (int i = 0; i < 16; ++i){
          int flat = i * 128 + tid, r = flat >> 5, c = flat & 31;
          sT[r * 33 + c] = ldin(u, (k0 + r) * 128 + y0 + c, isbf);
        }
        __syncthreads();
        float kmv = ldin(K, l * 64 + kl, isbf); kmv = fmaxf(kmv, 0.f);
        #pragma unroll
        for (int i = 0; i < 16; ++i){
          int yl = 2 * i + (tid >> 6);
          W2T[(y0 + yl) * W2T_STRIDE + k0 + kl] = (__bf16)(kmv * sT[kl * 33 + yl]);
        }
      }
    } else {
      float* sE = (float*)smem;            // 64 x 65
      const int y0 = (bid - 384) * 64;
      const int kl = tid & 63;
      #pragma unroll
      for (int i = 0; i < 32; ++i){
        int flat = i * 128 + tid, a = flat >> 6, c = flat & 63;
        sE[a * 65 + c] = ldin(e, a * 128 + y0 + c, isbf);
      }
      __syncthreads();
      #pragma unroll
      for (int i = 0; i < 32; ++i){
        int yl = 2 * i + (tid >> 6);
        W2T[(y0 + yl) * W2T_STRIDE + 4096 + kl] = (__bf16)sE[kl * 65 + yl];
      }
    }
    return;
  }

  // ---- iteration block ----
  float* sKf = (float*)smem;               // 64 x 65 relu(K) f32
  #pragma unroll
  for (int i = 0; i < 32; ++i){
    int idx = i * 128 + tid, l = idx >> 6, a = idx & 63;
    float v = ldin(K, idx, isbf);
    sKf[l * 65 + a] = fmaxf(v, 0.f);
  }
  __syncthreads();

  const int w = tid >> 6, lane = tid & 63;
  const int lr = lane & 15, q = lane >> 4;
  const int row0 = bid * 16;
  __bf16* sH = (__bf16*)(smem + 16640 + w * 4608);
  __bf16* sL = sH + 2304 / 2;              // +2304 bytes = 1152 elems

  const bf16x4 z4 = {(__bf16)0.f, (__bf16)0.f, (__bf16)0.f, (__bf16)0.f};
  for (int i = lane; i < 288; i += 64){
    *(bf16x4*)(sH + 4 * i) = z4;
    *(bf16x4*)(sL + 4 * i) = z4;
  }

  // A-fragments from LDS-staged relu(K): chain0 (AF): M1=Km, M2=KT; chain1 (LF): swapped
  bf16x8 a1[4][2], a2[4][2];
  #pragma unroll
  for (int T = 0; T < 4; ++T)
    #pragma unroll
    for (int ks = 0; ks < 2; ++ks){
      bf16x8 f1, f2;
      #pragma unroll
      for (int j = 0; j < 8; ++j){
        float vKm = sKf[(16 * T + lr) * 65 + ks * 32 + q * 8 + j];
        float vKT = sKf[(ks * 32 + q * 8 + j) * 65 + 16 * T + lr];
        f1[j] = (__bf16)(w ? vKT : vKm);
        f2[j] = (__bf16)(w ? vKm : vKT);
      }
      a1[T][ks] = f1; a2[T][ks] = f2;
    }

  float4v ltv[4], atv[4];
  if (isbf){
    const unsigned short* lt = (const unsigned short*)LT + (row0 + lr) * 64;
    const unsigned short* at = (const unsigned short*)AT;
    #pragma unroll
    for (int T = 0; T < 4; ++T)
      #pragma unroll
      for (int r = 0; r < 4; ++r){
        int d = 16 * T + q * 4 + r;
        ltv[T][r] = bf2f(lt[d]);
        atv[T][r] = fmaxf(bf2f(at[d]), 0.f);
      }
  } else {
    const float* lt = (const float*)LT + (row0 + lr) * 64;
    const float* at = (const float*)AT;
    #pragma unroll
    for (int T = 0; T < 4; ++T){
      ltv[T] = *(const float4v*)(lt + 16 * T + q * 4);
      float4v a = *(const float4v*)(at + 16 * T + q * 4);
      #pragma unroll
      for (int r = 0; r < 4; ++r) atv[T][r] = fmaxf(a[r], 0.f);
    }
  }
  float4v V1[4], V2[4];
  #pragma unroll
  for (int T = 0; T < 4; ++T){
    V1[T] = w ? atv[T] : ltv[T];
    V2[T] = w ? ltv[T] : atv[T];
  }

  int mi = msin[0];
  if (mi <= 0 || mi > 1000000){
    float mf = ((const float*)msin)[0];
    mi = (mf > 0.f && mf < 1.0e6f) ? (int)mf : 50;
  }

  const int rb = lr * 72 + q * 8;
  const int wb = lr * 72 + q * 4;

  const int nPlain = mi > 6 ? mi - 6 : 0;
  const int nSplit = mi - nPlain;
  for (int s = 0; s < nPlain; ++s){
    halfstep<false>(a1, V1, sH, sL, rb, wb);
    halfstep<false>(a2, V2, sH, sL, rb, wb);
  }
  for (int s = 0; s < nSplit; ++s){
    halfstep<true>(a1, V1, sH, sL, rb, wb);
    halfstep<true>(a2, V2, sH, sL, rb, wb);
  }
  // final extra step (reference computes one more step_fn after the loop)
  halfstep<true>(a1, V1, sH, sL, rb, wb);
  halfstep<true>(a2, V2, sH, sL, rb, wb);

  // coalesced write-out of final state (hi)
  __bf16* gX = (w ? gLF : gAF) + row0 * 64;
  const int lrow = lane >> 2, seg = lane & 3;
  bf16x8 v0 = *(const bf16x8*)(sH + lrow * 72 + seg * 16);
  bf16x8 v1 = *(const bf16x8*)(sH + lrow * 72 + seg * 16 + 8);
  *(bf16x8*)(gX + lrow * 64 + seg * 16) = v0;
  *(bf16x8*)(gX + lrow * 64 + seg * 16 + 8) = v1;
}

// ---------------- epilogue ----------------
// grid 128 x 256: block = 64 rows x 64 y-cols; wave = 32 rows (2 A-tiles) x 32 y.
__global__ __launch_bounds__(256) void k_epi(
    const __bf16* gAF, const __bf16* gLF, const __bf16* W2T,
    const void* bvec, void* out)
{
  __shared__ __attribute__((aligned(16))) __bf16 sAF[64 * 72], sLF[64 * 72];
  const int tid = threadIdx.x, wv = tid >> 6, lane = tid & 63;
  const int lr = lane & 15, q = lane >> 4;

  int ok = 0;
  if (tid < 64){
    float v = bf2f(((const unsigned short*)bvec)[tid]);
    ok = (v >= 0.f && v <= 1.0f) ? 1 : 0;
  }
  int cnt = __syncthreads_count(ok);
  const bool isbf = (cnt >= 60);

  const int rg = blockIdx.x >> 1, yh = blockIdx.x & 1;
  const int rows0 = rg * 64;
  {
    int lrow = tid >> 2, seg = tid & 3;
    *(bf16x8*)(sAF + lrow * 72 + seg * 16) =
        *(const bf16x8*)(gAF + (rows0 + lrow) * 64 + seg * 16);
    *(bf16x8*)(sAF + lrow * 72 + seg * 16 + 8) =
        *(const bf16x8*)(gAF + (rows0 + lrow) * 64 + seg * 16 + 8);
    *(bf16x8*)(sLF + lrow * 72 + seg * 16) =
        *(const bf16x8*)(gLF + (rows0 + lrow) * 64 + seg * 16);
    *(bf16x8*)(sLF + lrow * 72 + seg * 16 + 8) =
        *(const bf16x8*)(gLF + (rows0 + lrow) * 64 + seg * 16 + 8);
  }
  __syncthreads();

  const int r0w = (wv & 1) * 32;
  const int y0 = yh * 64 + (wv >> 1) * 32;

  const float bv0 = ldin(bvec, y0 + lr, isbf);
  const float bv1 = ldin(bvec, y0 + 16 + lr, isbf);
  float4v acc[2][2];
  acc[0][0] = float4v{bv0, bv0, bv0, bv0};
  acc[0][1] = float4v{bv1, bv1, bv1, bv1};
  acc[1][0] = acc[0][0];
  acc[1][1] = acc[0][1];

  bf16x8 afr[2][2];
  float aff[2][2][8];
  #pragma unroll
  for (int at = 0; at < 2; ++at){
    const int rloc = r0w + at * 16 + lr;
    afr[at][0] = *(const bf16x8*)(sAF + rloc * 72 + q * 8);
    afr[at][1] = *(const bf16x8*)(sAF + rloc * 72 + 32 + q * 8);
    #pragma unroll
    for (int j = 0; j < 8; ++j){
      aff[at][0][j] = (float)afr[at][0][j];
      aff[at][1][j] = (float)afr[at][1][j];
    }
  }

  const __bf16* w0 = W2T + (y0 + lr) * W2T_STRIDE + q * 8;
  const __bf16* w1 = w0 + 16 * W2T_STRIDE;

  #pragma unroll 2
  for (int l = 0; l < 64; ++l){
    const float lf0 = (float)sLF[(r0w + lr) * 72 + l];
    const float lf1 = (float)sLF[(r0w + 16 + lr) * 72 + l];
    bf16x8 aD[2][2];
    #pragma unroll
    for (int j = 0; j < 8; ++j){
      aD[0][0][j] = (__bf16)(lf0 * aff[0][0][j]);
      aD[0][1][j] = (__bf16)(lf0 * aff[0][1][j]);
      aD[1][0][j] = (__bf16)(lf1 * aff[1][0][j]);
      aD[1][1][j] = (__bf16)(lf1 * aff[1][1][j]);
    }
    const int kb = l * 64;
    bf16x8 b00 = *(const bf16x8*)(w0 + kb);
    bf16x8 b01 = *(const bf16x8*)(w0 + kb + 32);
    bf16x8 b10 = *(const bf16x8*)(w1 + kb);
    bf16x8 b11 = *(const bf16x8*)(w1 + kb + 32);
    acc[0][0] = MFMA16(aD[0][0], b00, acc[0][0], 0, 0, 0);
    acc[0][0] = MFMA16(aD[0][1], b01, acc[0][0], 0, 0, 0);
    acc[0][1] = MFMA16(aD[0][0], b10, acc[0][1], 0, 0, 0);
    acc[0][1] = MFMA16(aD[0][1], b11, acc[0][1], 0, 0, 0);
    acc[1][0] = MFMA16(aD[1][0], b00, acc[1][0], 0, 0, 0);
    acc[1][0] = MFMA16(aD[1][1], b01, acc[1][0], 0, 0, 0);
    acc[1][1] = MFMA16(aD[1][0], b10, acc[1][1], 0, 0, 0);
    acc[1][1] = MFMA16(aD[1][1], b11, acc[1][1], 0, 0, 0);
  }
  // e-term: k = 4096..4159, A-operand = AF raw
  {
    bf16x8 b00 = *(const bf16x8*)(w0 + 4096);
    bf16x8 b01 = *(const bf16x8*)(w0 + 4096 + 32);
    bf16x8 b10 = *(const bf16x8*)(w1 + 4096);
    bf16x8 b11 = *(const bf16x8*)(w1 + 4096 + 32);
    #pragma unroll
    for (int at = 0; at < 2; ++at){
      acc[at][0] = MFMA16(afr[at][0], b00, acc[at][0], 0, 0, 0);
      acc[at][0] = MFMA16(afr[at][1], b01, acc[at][0], 0, 0, 0);
      acc[at][1] = MFMA16(afr[at][0], b10, acc[at][1], 0, 0, 0);
      acc[at][1] = MFMA16(afr[at][1], b11, acc[at][1], 0, 0, 0);
    }
  }

  if (isbf){
    unsigned short* o = (unsigned short*)out;
    #pragma unroll
    for (int at = 0; at < 2; ++at)
      #pragma unroll
      for (int r = 0; r < 4; ++r){
        int orow = rows0 + r0w + at * 16 + q * 4 + r;
        o[orow * 128 + y0 + lr]      = f2bf(acc[at][0][r]);
        o[orow * 128 + y0 + 16 + lr] = f2bf(acc[at][1][r]);
      }
  } else {
    float* o = (float*)out;
    #pragma unroll
    for (int at = 0; at < 2; ++at)
      #pragma unroll
      for (int r = 0; r < 4; ++r){
        int orow = rows0 + r0w + at * 16 + q * 4 + r;
        o[orow * 128 + y0 + lr]      = acc[at][0][r];
        o[orow * 128 + y0 + 16 + lr] = acc[at][1][r];
      }
  }
}

extern "C" void kernel_launch(void* const* d_in, const int* in_sizes, int n_in,
                              void* d_out, int out_size, void* d_ws, size_t ws_size,
                              hipStream_t stream){
  char* ws = (char*)d_ws;
  __bf16* gAF = (__bf16*)(ws);
  __bf16* gLF = (__bf16*)(ws + 524288);
  __bf16* W2T = (__bf16*)(ws + 1048576);

  k_fused<<<dim3(386), dim3(128), 0, stream>>>(
      d_in[0], d_in[1], d_in[2], d_in[3], d_in[4], (const int*)d_in[6],
      gAF, gLF, W2T);
  k_epi<<<dim3(128), dim3(256), 0, stream>>>(
      gAF, gLF, W2T, d_in[5], d_out);
}

// Round 6
// 117.040 us; speedup vs baseline: 1.2167x; 1.1965x over previous
//
#include <hip/hip_runtime.h>
#include <hip/hip_bf16.h>

typedef _Float16 half8 __attribute__((ext_vector_type(8)));
typedef _Float16 h2    __attribute__((ext_vector_type(2)));
typedef float  float4v __attribute__((ext_vector_type(4)));

#define MFMAH __builtin_amdgcn_mfma_f32_16x16x32_f16
#define W2S 4160

union U8 { half8 v; h2 p[4]; int i[4]; };

__device__ __forceinline__ h2 pkrtz(float a, float b){
  auto r = __builtin_amdgcn_cvt_pkrtz(a, b);
  h2 o;
  __builtin_memcpy(&o, &r, sizeof(o));
  return o;
}
__device__ __forceinline__ float bf2f(unsigned short u){
  union { unsigned int i; float f; } x; x.i = ((unsigned int)u) << 16; return x.f;
}
__device__ __forceinline__ unsigned short f2bf(float f){
  union { float f; unsigned int i; } x; x.f = f;
  unsigned int r = x.i + 0x7FFFu + ((x.i >> 16) & 1u);
  return (unsigned short)(r >> 16);
}
__device__ __forceinline__ float ldin(const void* p, int i, bool isbf){
  return isbf ? bf2f(((const unsigned short*)p)[i]) : ((const float*)p)[i];
}
__device__ __forceinline__ float frcp(float x){ return __builtin_amdgcn_rcpf(x); }

// ws layout (bytes):
//   0       : gAF f16[4096*64]
//   524288  : gLF f16[4096*64]
//   1048576 : W2T f16[128][4160]  (k<4096 -> Km*u ; 4096..4159 -> e)

// register-resident halfstep: out = V * rcp(M @ x + 1); state stays in B0/B1
// (kappa-permuted A-frags make C-output packs == next B-operand, no LDS).
__device__ __forceinline__ void hstep_plain(const half8 (&A)[4][2], const float4v (&V)[4],
                                            half8& B0, half8& B1)
{
  const float4v ones = {1.f,1.f,1.f,1.f};
  float4v c[4];
  #pragma unroll
  for (int T = 0; T < 4; ++T) c[T] = MFMAH(A[T][0], B0, ones, 0, 0, 0);
  #pragma unroll
  for (int T = 0; T < 4; ++T) c[T] = MFMAH(A[T][1], B1, c[T], 0, 0, 0);
  U8 n0, n1;
  #pragma unroll
  for (int T = 0; T < 4; ++T){
    float o0 = V[T][0] * frcp(c[T][0]);
    float o1 = V[T][1] * frcp(c[T][1]);
    float o2 = V[T][2] * frcp(c[T][2]);
    float o3 = V[T][3] * frcp(c[T][3]);
    h2 pa = pkrtz(o0, o1);
    h2 pb = pkrtz(o2, o3);
    if (T < 2){ n0.p[2*T] = pa; n0.p[2*T+1] = pb; }
    else      { n1.p[2*(T-2)] = pa; n1.p[2*(T-2)+1] = pb; }
  }
  B0 = n0.v; B1 = n1.v;
}

__device__ __forceinline__ float hstep_err(const half8 (&A)[4][2], const float4v (&V)[4],
                                           half8& B0, half8& B1, float4v (&old)[4])
{
  const float4v ones = {1.f,1.f,1.f,1.f};
  float4v c[4];
  #pragma unroll
  for (int T = 0; T < 4; ++T) c[T] = MFMAH(A[T][0], B0, ones, 0, 0, 0);
  #pragma unroll
  for (int T = 0; T < 4; ++T) c[T] = MFMAH(A[T][1], B1, c[T], 0, 0, 0);
  U8 n0, n1;
  float worst = -1.f;
  #pragma unroll
  for (int T = 0; T < 4; ++T){
    float4v o;
    #pragma unroll
    for (int r = 0; r < 4; ++r){
      o[r] = V[T][r] * frcp(c[T][r]);
      float thr = old[T][r] * 6e-4f + 6e-9f;       // per-chain TOL=6e-4
      worst = fmaxf(worst, fabsf(o[r] - old[T][r]) - thr);
    }
    old[T] = o;
    h2 pa = pkrtz(o[0], o[1]);
    h2 pb = pkrtz(o[2], o[3]);
    if (T < 2){ n0.p[2*T] = pa; n0.p[2*T+1] = pb; }
    else      { n1.p[2*(T-2)] = pa; n1.p[2*(T-2)+1] = pb; }
  }
  B0 = n0.v; B1 = n1.v;
  return worst;
}

// ---------------- fused prep + iteration ----------------
// grid 386 x 128: bid<256 iter (wave0=AF-chain, wave1=LF-chain, 16 rows);
// 256..383 W2T u-builders (2 tiles each); 384..385 e-builders.
__global__ __launch_bounds__(128, 1) void k_fused(
    const void* LT, const void* K, const void* AT, const void* u,
    const void* e, const int* msin,
    _Float16* gAF, _Float16* gLF, _Float16* W2T)
{
  __shared__ __attribute__((aligned(16))) float sKf[64 * 65];  // 16640 B, reused by builders
  const int tid = threadIdx.x, bid = blockIdx.x;

  int ok = 0;
  if (tid < 64){
    float v = bf2f(((const unsigned short*)AT)[tid]);
    ok = (v >= 0.f && v <= 1.0f) ? 1 : 0;
  }
  int cnt = __syncthreads_count(ok);
  const bool isbf = (cnt >= 60);

  if (bid >= 256){
    if (bid < 384){
      float* sT = sKf;                      // 64 x 33
      const int ub = bid - 256;
      const int kl = tid & 63;
      for (int t2 = 0; t2 < 2; ++t2){
        const int t = ub * 2 + t2;
        const int k0 = (t >> 2) * 64, y0 = (t & 3) * 32, l = t >> 2;
        __syncthreads();
        #pragma unroll
        for (int i = 0; i < 16; ++i){
          int flat = i * 128 + tid, r = flat >> 5, c = flat & 31;
          sT[r * 33 + c] = ldin(u, (k0 + r) * 128 + y0 + c, isbf);
        }
        __syncthreads();
        float kmv = ldin(K, l * 64 + kl, isbf); kmv = fmaxf(kmv, 0.f);
        #pragma unroll
        for (int i = 0; i < 16; ++i){
          int yl = 2 * i + (tid >> 6);
          W2T[(y0 + yl) * W2S + k0 + kl] = (_Float16)(kmv * sT[kl * 33 + yl]);
        }
      }
    } else {
      float* sE = sKf;                      // 64 x 65
      const int y0 = (bid - 384) * 64;
      const int kl = tid & 63;
      #pragma unroll
      for (int i = 0; i < 32; ++i){
        int flat = i * 128 + tid, a = flat >> 6, c = flat & 63;
        sE[a * 65 + c] = ldin(e, a * 128 + y0 + c, isbf);
      }
      __syncthreads();
      #pragma unroll
      for (int i = 0; i < 32; ++i){
        int yl = 2 * i + (tid >> 6);
        W2T[(y0 + yl) * W2S + 4096 + kl] = (_Float16)sE[kl * 65 + yl];
      }
    }
    return;
  }

  // ---- iteration block ----
  #pragma unroll
  for (int i = 0; i < 32; ++i){
    int idx = i * 128 + tid, l = idx >> 6, a = idx & 63;
    sKf[l * 65 + a] = fmaxf(ldin(K, idx, isbf), 0.f);
  }
  __syncthreads();

  const int w = tid >> 6, lane = tid & 63;
  const int lr = lane & 15, q = lane >> 4;
  const int row0 = bid * 16;

  // kappa-permuted A-frags: element j multiplies state phys dim
  // kcol = 32ks + 16(j>>2) + 4q + (j&3); row m = 16T + lr.
  half8 a1[4][2], a2[4][2];
  #pragma unroll
  for (int T = 0; T < 4; ++T)
    #pragma unroll
    for (int ks = 0; ks < 2; ++ks){
      half8 f1, f2;
      #pragma unroll
      for (int j = 0; j < 8; ++j){
        int kcol = ks * 32 + ((j >> 2) * 16) + q * 4 + (j & 3);
        int row  = 16 * T + lr;
        float vKm = sKf[row * 65 + kcol];
        float vKT = sKf[kcol * 65 + row];
        f1[j] = (_Float16)(w ? vKT : vKm);
        f2[j] = (_Float16)(w ? vKm : vKT);
      }
      a1[T][ks] = f1; a2[T][ks] = f2;
    }

  float4v ltv[4], atv[4];
  if (isbf){
    const unsigned short* lt = (const unsigned short*)LT + (row0 + lr) * 64;
    const unsigned short* at = (const unsigned short*)AT;
    #pragma unroll
    for (int T = 0; T < 4; ++T)
      #pragma unroll
      for (int r = 0; r < 4; ++r){
        int d = 16 * T + q * 4 + r;
        ltv[T][r] = bf2f(lt[d]);
        atv[T][r] = fmaxf(bf2f(at[d]), 0.f);
      }
  } else {
    const float* lt = (const float*)LT + (row0 + lr) * 64;
    const float* at = (const float*)AT;
    #pragma unroll
    for (int T = 0; T < 4; ++T){
      ltv[T] = *(const float4v*)(lt + 16 * T + q * 4);
      float4v a = *(const float4v*)(at + 16 * T + q * 4);
      #pragma unroll
      for (int r = 0; r < 4; ++r) atv[T][r] = fmaxf(a[r], 0.f);
    }
  }
  float4v V1[4], V2[4];
  #pragma unroll
  for (int T = 0; T < 4; ++T){
    V1[T] = w ? atv[T] : ltv[T];
    V2[T] = w ? ltv[T] : atv[T];
  }

  int mi = msin[0];
  if (mi < 0 || mi > 1000000){
    float mf = ((const float*)msin)[0];
    mi = (mf >= 0.f && mf < 1.0e6f) ? (int)mf : 50;
  }

  half8 B0 = {}, B1 = {};
  float4v old[4] = {};

  int conv = 0;
  for (int s = 0; s < mi && !conv; ++s){
    hstep_plain(a1, V1, B0, B1);
    float worst = hstep_err(a2, V2, B0, B1, old);
    conv = (__ballot(worst > 0.f) == 0ULL) ? 1 : 0;
  }
  // reference's post-loop extra step_fn
  hstep_plain(a1, V1, B0, B1);
  hstep_plain(a2, V2, B0, B1);

  // write final state (natural [row][dim] order, fp16)
  _Float16* gX = (w ? gLF : gAF) + (row0 + lr) * 64;
  int* g32 = (int*)gX;
  U8 ub0, ub1; ub0.v = B0; ub1.v = B1;
  #pragma unroll
  for (int T = 0; T < 4; ++T){
    int base = 8 * T + 2 * q;
    const U8& s = (T < 2) ? ub0 : ub1;
    g32[base]     = s.i[2 * (T & 1)];
    g32[base + 1] = s.i[2 * (T & 1) + 1];
  }
}

// ---------------- epilogue ----------------
// grid 256 x 256: block = 32 rows x 64 y; wave = 16 rows x 32 y.
__global__ __launch_bounds__(256) void k_epi(
    const _Float16* gAF, const _Float16* gLF, const _Float16* W2T,
    const void* bvec, void* out)
{
  __shared__ __attribute__((aligned(16))) _Float16 sAF[32 * 72], sLF[32 * 72];
  const int tid = threadIdx.x, wv = tid >> 6, lane = tid & 63;
  const int lr = lane & 15, q = lane >> 4;

  int ok = 0;
  if (tid < 64){
    float v = bf2f(((const unsigned short*)bvec)[tid]);
    ok = (v >= 0.f && v <= 1.0f) ? 1 : 0;
  }
  int cnt = __syncthreads_count(ok);
  const bool isbf = (cnt >= 60);

  const int rows0 = (blockIdx.x >> 1) * 32, yh = blockIdx.x & 1;
  {
    int lrow = tid >> 3, seg = tid & 7;
    *(half8*)(sAF + lrow * 72 + seg * 8) =
        *(const half8*)(gAF + (rows0 + lrow) * 64 + seg * 8);
    *(half8*)(sLF + lrow * 72 + seg * 8) =
        *(const half8*)(gLF + (rows0 + lrow) * 64 + seg * 8);
  }
  __syncthreads();

  const int r0 = (wv & 1) * 16;
  const int y0 = yh * 64 + (wv >> 1) * 32;
  const int rloc = r0 + lr;

  const float bv0 = ldin(bvec, y0 + lr, isbf);
  const float bv1 = ldin(bvec, y0 + 16 + lr, isbf);
  float4v acc0 = {bv0, bv0, bv0, bv0};
  float4v acc1 = {bv1, bv1, bv1, bv1};

  U8 uaf0, uaf1;
  uaf0.v = *(const half8*)(sAF + rloc * 72 + q * 8);
  uaf1.v = *(const half8*)(sAF + rloc * 72 + 32 + q * 8);

  const _Float16* w0 = W2T + (y0 + lr) * W2S + q * 8;
  const _Float16* w1 = w0 + 16 * W2S;

  #pragma unroll 4
  for (int l = 0; l < 64; ++l){
    _Float16 lfv = sLF[rloc * 72 + l];
    h2 lf2 = {lfv, lfv};
    U8 d0, d1;
    #pragma unroll
    for (int i = 0; i < 4; ++i){
      d0.p[i] = lf2 * uaf0.p[i];            // v_pk_mul_f16
      d1.p[i] = lf2 * uaf1.p[i];
    }
    const int kb = l * 64;
    half8 b00 = *(const half8*)(w0 + kb);
    half8 b01 = *(const half8*)(w0 + kb + 32);
    half8 b10 = *(const half8*)(w1 + kb);
    half8 b11 = *(const half8*)(w1 + kb + 32);
    acc0 = MFMAH(d0.v, b00, acc0, 0, 0, 0);
    acc0 = MFMAH(d1.v, b01, acc0, 0, 0, 0);
    acc1 = MFMAH(d0.v, b10, acc1, 0, 0, 0);
    acc1 = MFMAH(d1.v, b11, acc1, 0, 0, 0);
  }
  {  // e-term: k = 4096..4159, A-operand = AF raw
    half8 b00 = *(const half8*)(w0 + 4096);
    half8 b01 = *(const half8*)(w0 + 4096 + 32);
    half8 b10 = *(const half8*)(w1 + 4096);
    half8 b11 = *(const half8*)(w1 + 4096 + 32);
    acc0 = MFMAH(uaf0.v, b00, acc0, 0, 0, 0);
    acc0 = MFMAH(uaf1.v, b01, acc0, 0, 0, 0);
    acc1 = MFMAH(uaf0.v, b10, acc1, 0, 0, 0);
    acc1 = MFMAH(uaf1.v, b11, acc1, 0, 0, 0);
  }

  if (isbf){
    unsigned short* o = (unsigned short*)out;
    #pragma unroll
    for (int r = 0; r < 4; ++r){
      int orow = rows0 + r0 + q * 4 + r;
      o[orow * 128 + y0 + lr]      = f2bf(acc0[r]);
      o[orow * 128 + y0 + 16 + lr] = f2bf(acc1[r]);
    }
  } else {
    float* o = (float*)out;
    #pragma unroll
    for (int r = 0; r < 4; ++r){
      int orow = rows0 + r0 + q * 4 + r;
      o[orow * 128 + y0 + lr]      = acc0[r];
      o[orow * 128 + y0 + 16 + lr] = acc1[r];
    }
  }
}

extern "C" void kernel_launch(void* const* d_in, const int* in_sizes, int n_in,
                              void* d_out, int out_size, void* d_ws, size_t ws_size,
                              hipStream_t stream){
  char* ws = (char*)d_ws;
  _Float16* gAF = (_Float16*)(ws);
  _Float16* gLF = (_Float16*)(ws + 524288);
  _Float16* W2T = (_Float16*)(ws + 1048576);

  k_fused<<<dim3(386), dim3(128), 0, stream>>>(
      d_in[0], d_in[1], d_in[2], d_in[3], d_in[4], (const int*)d_in[6],
      gAF, gLF, W2T);
  k_epi<<<dim3(256), dim3(256), 0, stream>>>(
      gAF, gLF, W2T, d_in[5], d_out);
}